// Round 4
// baseline (368.897 us; speedup 1.0000x reference)
//
#include <hip/hip_runtime.h>

typedef _Float16 f16;
typedef _Float16 f16x8 __attribute__((ext_vector_type(8)));
typedef float f32x4 __attribute__((ext_vector_type(4)));

__device__ __forceinline__ void gload_lds16(const void* g, void* l) {
  __builtin_amdgcn_global_load_lds((const __attribute__((address_space(1))) void*)g,
                                   (__attribute__((address_space(3))) void*)l, 16, 0, 0);
}

__device__ __forceinline__ f32x4 mfma16(f16x8 a, f16x8 b, f32x4 c) {
  return __builtin_amdgcn_mfma_f32_16x16x32_f16(a, b, c, 0, 0, 0);
}

// ---------------- small prep kernels (unchanged) ----------------

__global__ void k_cvt(const float* __restrict__ src, f16* __restrict__ dst, int n8) {
  int i = blockIdx.x * 256 + threadIdx.x;
  if (i >= n8) return;
  const float4* s4 = reinterpret_cast<const float4*>(src) + (size_t)i * 2;
  float4 a = s4[0], b = s4[1];
  f16x8 v;
  v[0] = (f16)a.x; v[1] = (f16)a.y; v[2] = (f16)a.z; v[3] = (f16)a.w;
  v[4] = (f16)b.x; v[5] = (f16)b.y; v[6] = (f16)b.z; v[7] = (f16)b.w;
  *reinterpret_cast<f16x8*>(dst + (size_t)i * 8) = v;
}

__global__ void k_cvt_at(const float* __restrict__ A, f16* __restrict__ at) {
  __shared__ float t[64][65];
  int bi = blockIdx.x, br = blockIdx.y;
  int tx = threadIdx.x & 63, ty = threadIdx.x >> 6;
#pragma unroll
  for (int p = 0; p < 16; ++p) {
    int r = p * 4 + ty;
    t[r][tx] = A[(size_t)(br * 64 + r) * 4096 + bi * 64 + tx];
  }
  __syncthreads();
#pragma unroll
  for (int p = 0; p < 16; ++p) {
    int i = p * 4 + ty;
    at[(size_t)(bi * 64 + i) * 256 + br * 64 + tx] = (f16)t[tx][i];
  }
}

__device__ __forceinline__ void stage_tile_lin(const f16* __restrict__ g, size_t row0, int k0,
                                               int ldg, f16* s, int wid, int lane) {
#pragma unroll
  for (int t = 0; t < 4; ++t) {
    int c = (wid * 4 + t) * 64 + lane;
    const f16* gp = g + (row0 + (size_t)(c >> 3)) * (size_t)ldg + k0 + (c & 7) * 8;
    gload_lds16(gp, s + (wid * 4 + t) * 512);
  }
}

__global__ __launch_bounds__(256) void k_lora(const f16* __restrict__ bh,
                                              const f16* __restrict__ at,
                                              const float* __restrict__ base,
                                              f16* __restrict__ ch,
                                              float* __restrict__ partial) {
  __shared__ f16 sA[128 * 64];
  __shared__ f16 sB[128 * 64];
  __shared__ float ssum[2][128];
  int tid = threadIdx.x;
  int wid = tid >> 6, lane = tid & 63;
  int wm = wid >> 1, wn = wid & 1;
  int ln = lane & 15, q = lane >> 4;
  int bm = blockIdx.x >> 5, bn = blockIdx.x & 31;
  int brow = bm * 128, bcol = bn * 128;
  f32x4 acc[4][4] = {};
  for (int kt = 0; kt < 256; kt += 64) {
    __syncthreads();
    stage_tile_lin(bh, brow, kt, 256, sA, wid, lane);
    stage_tile_lin(at, bcol, kt, 256, sB, wid, lane);
    __syncthreads();
#pragma unroll
    for (int ks = 0; ks < 2; ++ks) {
      f16x8 af[4], bf[4];
#pragma unroll
      for (int mi = 0; mi < 4; ++mi)
        af[mi] = *reinterpret_cast<const f16x8*>(&sA[(wm * 64 + mi * 16 + ln) * 64 + ks * 32 + q * 8]);
#pragma unroll
      for (int ni = 0; ni < 4; ++ni)
        bf[ni] = *reinterpret_cast<const f16x8*>(&sB[(wn * 64 + ni * 16 + ln) * 64 + ks * 32 + q * 8]);
#pragma unroll
      for (int mi = 0; mi < 4; ++mi)
#pragma unroll
        for (int ni = 0; ni < 4; ++ni)
          acc[mi][ni] = mfma16(af[mi], bf[ni], acc[mi][ni]);
    }
  }
#pragma unroll
  for (int mi = 0; mi < 4; ++mi) {
#pragma unroll
    for (int j = 0; j < 4; ++j) {
      int row = brow + wm * 64 + mi * 16 + q * 4 + j;
      float s = 0.f;
#pragma unroll
      for (int ni = 0; ni < 4; ++ni) {
        int col = bcol + wn * 64 + ni * 16 + ln;
        float v = base[(size_t)row * 4096 + col] + 0.5f * acc[mi][ni][j];
        ch[(size_t)row * 4096 + col] = (f16)v;
        s += v * v;
      }
#pragma unroll
      for (int m = 1; m < 16; m <<= 1) s += __shfl_xor(s, m, 64);
      if (ln == 0) ssum[wn][wm * 64 + mi * 16 + q * 4 + j] = s;
    }
  }
  __syncthreads();
  if (tid < 128) {
    float p = ssum[0][tid] + ssum[1][tid];
    partial[(size_t)(brow + tid) * 32 + bn] = p;
  }
}

__global__ void k_scale(const float* __restrict__ partial, const float* __restrict__ mag,
                        const float* __restrict__ turk, float* __restrict__ scale) {
  int o = blockIdx.x * 256 + threadIdx.x;
  float s = 0.f;
#pragma unroll
  for (int c = 0; c < 32; ++c) s += partial[(size_t)o * 32 + c];
  scale[o] = mag[o] * turk[o] / (sqrtf(s) + 1e-8f);
}

// ---------------- 256x256 8-phase main GEMM ----------------
// Waves 2M x 4N, per-wave out 128x64, acc[8][4].
// LDS half = [128 rows][8 slots x 8 f16], slot XOR (row&7).
// Staging via 4 per-thread running pointers (+64 elts/K-tile).

__device__ __forceinline__ void stage2(const f16* p, f16* d) {
  gload_lds16(p, d);                 // chunk l=0
  gload_lds16(p + 32768, d + 512);   // chunk l=1: +8 rows global, +512 f16 LDS
}

__device__ __forceinline__ void lda4(const f16* base, int g, int ln, int sw, f16x8 (&af)[4]) {
#pragma unroll
  for (int f = 0; f < 4; ++f)
    af[f] = *reinterpret_cast<const f16x8*>(base + (g * 64 + f * 16 + ln) * 64 + sw);
}

__device__ __forceinline__ void ldb4(const f16* base, int ln, int sw, f16x8 (&bf)[4]) {
#pragma unroll
  for (int n = 0; n < 4; ++n)
    bf[n] = *reinterpret_cast<const f16x8*>(base + (n * 16 + ln) * 64 + sw);
}

template <int G>
__device__ __forceinline__ void mfma16x(f16x8 (&af)[4], f16x8 (&bf)[4], f32x4 (&acc)[8][4]) {
#pragma unroll
  for (int f = 0; f < 4; ++f)
#pragma unroll
    for (int n = 0; n < 4; ++n)
      acc[G * 4 + f][n] = mfma16(af[f], bf[n], acc[G * 4 + f][n]);
}

__global__ __launch_bounds__(512, 2) void k_main(const f16* __restrict__ xh,
                                                 const f16* __restrict__ ch,
                                                 const float* __restrict__ scale,
                                                 const float* __restrict__ bias,
                                                 float* __restrict__ out) {
  __shared__ __align__(16) f16 sA[32768];   // 2 bufs x 2 halves x 128x64
  __shared__ __align__(16) f16 sB[32768];
  int tid = threadIdx.x;
  int wid = tid >> 6, lane = tid & 63;
  int wm = wid >> 2, wn = wid & 3;          // 2M x 4N
  int ln = lane & 15, q8 = lane >> 4;
  int sw0 = (q8 ^ (ln & 7)) * 8;
  int sw1 = ((4 + q8) ^ (ln & 7)) * 8;

  int bid = blockIdx.x;
  int swz = (bid & 7) * 64 + (bid >> 3);    // XCD-aware, bijective (512 % 8 == 0)
  int bm = swz >> 4, bn = swz & 15;
  size_t brow = (size_t)bm * 256;
  int bcol = bn * 256;

  f32x4 acc[8][4] = {};
  f16x8 af0[4], af1[4], af2[4], af3[4], bf0[4], bf1[4];

  const int aOff = wm * 8192;
  const int bOff = (wn >> 1) * 8192 + (wn & 1) * 4096;

  // per-thread staging pointers (chunk l=0); l=1 is +32768 elts
  int rloc = wid * 16 + (lane >> 3);
  int swcol = ((lane & 7) ^ ((lane >> 3) & 7)) * 8;
  const f16* pa0 = xh + (brow + rloc) * 4096 + swcol;
  const f16* pa1 = pa0 + 128 * 4096;
  const f16* pb0 = ch + ((size_t)bcol + rloc) * 4096 + swcol;
  const f16* pb1 = pb0 + 128 * 4096;
  f16* myA = sA + wid * 1024;               // wave-uniform LDS base, chunk l=0
  f16* myB = sB + wid * 1024;

  // prologue: t0 full -> buf0; t1 A-halves -> buf1
  stage2(pa0, myA);
  stage2(pa1, myA + 8192);
  stage2(pb0, myB);
  stage2(pb1, myB + 8192);
  stage2(pa1 + 64, myA + 16384 + 8192);
  stage2(pa0 + 64, myA + 16384);
  pa0 += 128; pa1 += 128; pb0 += 64; pb1 += 64;
  asm volatile("s_waitcnt vmcnt(4)");
  __builtin_amdgcn_s_barrier();

#define KTILE(CUR, SB, SA, WVM)                                                              \
  {                                                                                          \
    const int NC = (CUR) ^ 1;                                                                \
    const f16* cA = sA + (CUR) * 16384 + aOff;                                               \
    const f16* cB = sB + (CUR) * 16384 + bOff;                                               \
    /* ph0: reads af0,bf0 (8); stage B(t+1)h0 -> buf[NC] */                                  \
    lda4(cA, 0, ln, sw0, af0); ldb4(cB, ln, sw0, bf0);                                       \
    if (SB) { stage2(pb0, myB + NC * 16384); pb0 += 64; }                                    \
    __builtin_amdgcn_s_barrier();                                                            \
    asm volatile("s_waitcnt lgkmcnt(0)");                                                    \
    __builtin_amdgcn_s_setprio(1); mfma16x<0>(af0, bf0, acc); __builtin_amdgcn_s_setprio(0); \
    __builtin_amdgcn_s_barrier();                                                            \
    /* ph1: reads af1,bf1 (8); stage B(t+1)h1 -> buf[NC] */                                  \
    lda4(cA, 0, ln, sw1, af1); ldb4(cB, ln, sw1, bf1);                                       \
    if (SB) { stage2(pb1, myB + NC * 16384 + 8192); pb1 += 64; }                             \
    __builtin_amdgcn_s_barrier();                                                            \
    asm volatile("s_waitcnt lgkmcnt(0)");                                                    \
    __builtin_amdgcn_s_setprio(1); mfma16x<0>(af1, bf1, acc); __builtin_amdgcn_s_setprio(0); \
    __builtin_amdgcn_s_barrier();                                                            \
    /* ph2: reads af2 (4) */                                                                 \
    lda4(cA, 1, ln, sw0, af2);                                                               \
    __builtin_amdgcn_s_barrier();                                                            \
    asm volatile("s_waitcnt lgkmcnt(0)");                                                    \
    __builtin_amdgcn_s_setprio(1); mfma16x<1>(af2, bf0, acc); __builtin_amdgcn_s_setprio(0); \
    __builtin_amdgcn_s_barrier();                                                            \
    /* ph3: reads af3 (4); stage A(t+2)h1,h0 -> buf[CUR]; K-tile boundary wait */            \
    lda4(cA, 1, ln, sw1, af3);                                                               \
    if (SA) { stage2(pa1, myA + (CUR) * 16384 + 8192); pa1 += 64;                            \
              stage2(pa0, myA + (CUR) * 16384);        pa0 += 64; }                          \
    __builtin_amdgcn_s_barrier();                                                            \
    asm volatile("s_waitcnt lgkmcnt(0)");                                                    \
    __builtin_amdgcn_s_setprio(1); mfma16x<1>(af3, bf1, acc); __builtin_amdgcn_s_setprio(0); \
    asm volatile(WVM);                                                                       \
    __builtin_amdgcn_s_barrier();                                                            \
  }

  for (int t = 0; t < 62; t += 2) {
    KTILE(0, 1, 1, "s_waitcnt vmcnt(4)")
    KTILE(1, 1, 1, "s_waitcnt vmcnt(4)")
  }
  // drain: tile 62 stages B63 only, then full drain; tile 63 pure compute
  KTILE(0, 1, 0, "s_waitcnt vmcnt(0)")
  KTILE(1, 0, 0, "")
#undef KTILE

  // epilogue: out = scale[col]*acc + bias[col]
#pragma unroll
  for (int n = 0; n < 4; ++n) {
    int col = bcol + wn * 64 + n * 16 + ln;
    float sc = scale[col], bs = bias[col];
#pragma unroll
    for (int mf = 0; mf < 8; ++mf)
#pragma unroll
      for (int j = 0; j < 4; ++j) {
        size_t row = brow + wm * 128 + mf * 16 + q8 * 4 + j;
        out[row * 4096 + col] = sc * acc[mf][n][j] + bs;
      }
  }
}

extern "C" void kernel_launch(void* const* d_in, const int* in_sizes, int n_in,
                              void* d_out, int out_size, void* d_ws, size_t ws_size,
                              hipStream_t stream) {
  const float* x    = (const float*)d_in[0];
  const float* base = (const float*)d_in[1];
  const float* bias = (const float*)d_in[2];
  const float* lA   = (const float*)d_in[3];
  const float* lB   = (const float*)d_in[4];
  const float* mag  = (const float*)d_in[5];
  const float* turk = (const float*)d_in[6];
  float* out = (float*)d_out;
  char* ws = (char*)d_ws;

  f16*   xh      = (f16*)(ws);                        // 64 MiB
  f16*   ch      = (f16*)(ws + 67108864);             // 32 MiB
  f16*   at      = (f16*)(ws + 100663296);            //  2 MiB
  f16*   bh      = (f16*)(ws + 102760448);            //  2 MiB
  float* partial = (float*)(ws + 104857600);          // 512 KiB
  float* scale   = (float*)(ws + 105381888);          // 16 KiB

  k_cvt<<<16384, 256, 0, stream>>>(x, xh, 4194304);
  k_cvt<<<512, 256, 0, stream>>>(lB, bh, 131072);
  k_cvt_at<<<dim3(64, 4), 256, 0, stream>>>(lA, at);
  k_lora<<<1024, 256, 0, stream>>>(bh, at, base, ch, partial);
  k_scale<<<16, 256, 0, stream>>>(partial, mag, turk, scale);
  k_main<<<512, 512, 0, stream>>>(xh, ch, scale, bias, out);
}